// Round 8
// baseline (844.151 us; speedup 1.0000x reference)
//
#include <hip/hip_runtime.h>
#include <math.h>

#define NFEAT 128
#define NCLS 40
#define NCLSP 64      // padded class dim (bf16) for pow2 lane math
#define BINROWS 64    // rows per bin
#define NBINMAX 1600  // >= ceil(100000/64)=1563
#define NBLKC 256     // chunks for the binning sort
#define CHUNKMAX 6400 // >= ceil(1600000/256)=6250 ; LDS stage = 50KB
#define SEGC 7        // ceil(NBINMAX/256)
#define RSMAX 2048    // row_sort LDS stage (bin edges ~Poisson(1024); 2048 = +32 sigma)

typedef short bf16x8 __attribute__((ext_vector_type(8)));
typedef float f32x4 __attribute__((ext_vector_type(4)));

// ---------- bf16 helpers ----------
__device__ __forceinline__ float bf2f(unsigned int lo16) {
  return __uint_as_float((lo16 & 0xffffu) << 16);
}
__device__ __forceinline__ unsigned int f2bf(float x) {  // round-to-nearest-even
  unsigned int u = __float_as_uint(x);
  return (u + 0x7fffu + ((u >> 16) & 1u)) >> 16;
}

// ============================ BN param folding ============================
__global__ void bn_prep(const float* b0, const float* g0, const float* be0,
                        const float* rm0, const float* rv0,
                        const float* b1, const float* g1, const float* be1,
                        const float* rm1, const float* rv1,
                        float* sc0, float* sh0, float* sc1, float* sh1) {
  int t = threadIdx.x;
  if (t < 128) {
    float s = g0[t] * rsqrtf(rv0[t] + 1e-5f);
    sc0[t] = s;
    sh0[t] = (b0[t] - rm0[t]) * s + be0[t];
  } else {
    int i = t - 128;
    float s = g1[i] * rsqrtf(rv1[i] + 1e-5f);
    sc1[i] = s;
    sh1[i] = (b1[i] - rm1[i]) * s + be1[i];
  }
}

// ============================ input conversions ============================
// xm = bf16(M*x) stored as 8 feature-PLANES: plane p holds feats [16p,16p+16) of
// all rows (N x 16, 3.2MB) -> one plane fits one XCD's 4MiB L2 (slice residency).
__global__ void convert_xm(const float* __restrict__ x, const float* __restrict__ Mv,
                           unsigned short* __restrict__ xm, int n) {
  int i = blockIdx.x * 256 + threadIdx.x;  // one 8-feat chunk per thread
  if (i >= n * (NFEAT / 8)) return;
  int row = i >> 4;
  int f0 = (i & 15) * 8;
  float m = Mv[row];
  const float4* p = (const float4*)(x + (size_t)row * NFEAT + f0);
  float4 v0 = p[0], v1 = p[1];
  uint4 o;
  o.x = f2bf(v0.x * m) | (f2bf(v0.y * m) << 16);
  o.y = f2bf(v0.z * m) | (f2bf(v0.w * m) << 16);
  o.z = f2bf(v1.x * m) | (f2bf(v1.y * m) << 16);
  o.w = f2bf(v1.z * m) | (f2bf(v1.w * m) << 16);
  *(uint4*)(xm + (size_t)(f0 >> 4) * n * 16 + (size_t)row * 16 + (f0 & 8)) = o;
}

__global__ void convert_w(const float* __restrict__ W0, const float* __restrict__ W1,
                          unsigned short* __restrict__ Wb0, unsigned short* __restrict__ Wb1) {
  int i = blockIdx.x * 256 + threadIdx.x;  // 4096 threads, 8 elems each
  const float* W = (i < 2048) ? W0 : W1;
  unsigned short* Wb = (i < 2048) ? Wb0 : Wb1;
  int j = (i < 2048) ? i : i - 2048;
  const float4* p = (const float4*)(W + (size_t)j * 8);
  float4 v0 = p[0], v1 = p[1];
  unsigned int o0 = f2bf(v0.x) | (f2bf(v0.y) << 16);
  unsigned int o1 = f2bf(v0.z) | (f2bf(v0.w) << 16);
  unsigned int o2 = f2bf(v1.x) | (f2bf(v1.y) << 16);
  unsigned int o3 = f2bf(v1.z) | (f2bf(v1.w) << 16);
  ((uint4*)Wb)[j] = make_uint4(o0, o1, o2, o3);
}

// ============================ stage 1: chunk -> 64-row bins (LDS sort) ============================
__global__ __launch_bounds__(256) void bin_sort1(
    const int* __restrict__ srcp, const int* __restrict__ dstp, const float* __restrict__ valp,
    int2* __restrict__ Drm, int2* __restrict__ binsC, int E, int nbin, int chunk) {
  __shared__ int2 stage[CHUNKMAX];
  __shared__ int cur[NBINMAX];
  __shared__ int ps[256];
  const int t = threadIdx.x, k = blockIdx.x;
  for (int i = t; i < nbin; i += 256) cur[i] = 0;
  __syncthreads();
  const int e0 = k * chunk, e1 = min(E, e0 + chunk);
#pragma unroll 4
  for (int e = e0 + t; e < e1; e += 256) atomicAdd(&cur[dstp[e] >> 6], 1);
  __syncthreads();
  int loc[SEGC], cnt[SEGC];
  int s = 0;
#pragma unroll
  for (int j = 0; j < SEGC; ++j) {
    int i = t * SEGC + j;
    int v = (i < nbin) ? cur[i] : 0;
    loc[j] = s; cnt[j] = v;
    s += v;
  }
  ps[t] = s;
  __syncthreads();
  for (int o = 1; o < 256; o <<= 1) {
    int x = (t >= o) ? ps[t - o] : 0;
    __syncthreads();
    ps[t] += x;
    __syncthreads();
  }
  int ex = ps[t] - s;
#pragma unroll
  for (int j = 0; j < SEGC; ++j) {
    int i = t * SEGC + j;
    if (i < nbin) {
      int o = ex + loc[j];
      Drm[(size_t)k * nbin + i] = make_int2(e0 + o, cnt[j]);
      cur[i] = o;
    }
  }
  __syncthreads();
#pragma unroll 2
  for (int e = e0 + t; e < e1; e += 256) {
    int d = dstp[e];
    int p = atomicAdd(&cur[d >> 6], 1);
    stage[p] = make_int2(srcp[e] | ((d & 63) << 17), __float_as_int(valp[e]));
  }
  __syncthreads();
  const int n = e1 - e0;
  for (int i = t; i < n; i += 256) binsC[e0 + i] = stage[i];
}

// Transpose run descriptors (row-major by chunk -> bin-major) + per-bin totals.
__global__ __launch_bounds__(256) void transposeD1(
    const int2* __restrict__ Drm, int2* __restrict__ Dbm, int* __restrict__ binTot, int nbin) {
  __shared__ int2 st[8][256];
  __shared__ int part[256];
  int t = threadIdx.x;
  int i0 = blockIdx.x * 8;
#pragma unroll
  for (int j = 0; j < 8; ++j) {
    int i = i0 + j;
    st[j][t] = (i < nbin) ? Drm[(size_t)t * nbin + i] : make_int2(0, 0);
  }
  __syncthreads();
  {
    int j = t >> 5, ks = (t & 31) * 8;
    int i = i0 + j;
    if (i < nbin) {
      int2* q = &Dbm[(size_t)i * NBLKC + ks];
#pragma unroll
      for (int m = 0; m < 8; ++m) q[m] = st[j][ks + m];
    }
    int p = 0;
#pragma unroll
    for (int m = 0; m < 8; ++m) p += st[j][ks + m].y;
    part[t] = p;
  }
  __syncthreads();
  if (t < 8) {
    int s = 0;
    for (int k = 0; k < 32; ++k) s += part[t * 32 + k];
    if (i0 + t < nbin) binTot[i0 + t] = s;
  }
}

// Exclusive scan of binTot -> binStart (single block).
__global__ __launch_bounds__(256) void bin_start1(
    const int* __restrict__ bt, int* __restrict__ bs, int nbin) {
  __shared__ int ps[256];
  int t = threadIdx.x;
  int C = (nbin + 255) / 256;  // <= 7
  int loc[SEGC + 1];
  int sum = 0;
  for (int j = 0; j < C; ++j) {
    int i = t * C + j;
    loc[j] = sum;
    sum += (i < nbin) ? bt[i] : 0;
  }
  ps[t] = sum;
  __syncthreads();
  for (int o = 1; o < 256; o <<= 1) {
    int x = (t >= o) ? ps[t - o] : 0;
    __syncthreads();
    ps[t] += x;
    __syncthreads();
  }
  int ex = ps[t] - sum;
  for (int j = 0; j < C; ++j) {
    int i = t * C + j;
    if (i < nbin) bs[i] = ex + loc[j];
  }
  if (t == 255) bs[nbin] = ps[255];
}

// ============================ stage 2: bin -> full dst-row sort ============================
// One block per bin: gather the bin's edges from the 256 chunk-runs into LDS,
// sort by exact row, emit fully dst-sorted compact edge array + rowptr.
__global__ __launch_bounds__(256) void row_sort(
    const int2* __restrict__ Dbm, const int2* __restrict__ binsC,
    const int* __restrict__ binStart, int2* __restrict__ bins2,
    int* __restrict__ rowptr, int n, int nbin) {
  __shared__ int2 stage[RSMAX];
  __shared__ int ps[256];
  __shared__ int rcnt[BINROWS];
  __shared__ int roff[BINROWS];
  const int b = blockIdx.x, t = threadIdx.x;
  if (t < BINROWS) rcnt[t] = 0;
  int2 run = Dbm[(size_t)b * NBLKC + t];
  ps[t] = run.y;
  __syncthreads();
  for (int o = 1; o < 256; o <<= 1) {
    int x = (t >= o) ? ps[t - o] : 0;
    __syncthreads();
    ps[t] += x;
    __syncthreads();
  }
  int mystart = ps[t] - run.y;
  for (int j = 0; j < run.y; ++j) {
    int2 en = binsC[run.x + j];
    int idx = mystart + j;
    if (idx < RSMAX) stage[idx] = en;
    atomicAdd(&rcnt[(en.x >> 17) & 63], 1);
  }
  __syncthreads();
  const int bs = binStart[b];
  if (t < BINROWS) {  // wave 0 only: scan 64 row counts
    int c = rcnt[t];
    int s = c;
#pragma unroll
    for (int o = 1; o < 64; o <<= 1) {
      int v = __shfl_up(s, o);
      if (t >= o) s += v;
    }
    int excl = s - c;
    int row = b * BINROWS + t;
    if (row < n) rowptr[row] = bs + excl;
    roff[t] = excl;
  }
  __syncthreads();
  int total = min(ps[255], RSMAX);
  for (int i = t; i < total; i += 256) {
    int2 en = stage[i];
    int row = (en.x >> 17) & 63;
    int p = atomicAdd(&roff[row], 1);
    bins2[bs + p] = en;
  }
  if (b == nbin - 1 && t == 0) rowptr[n] = binStart[nbin];
}

// ============================ SPMM, XCD-sliced (16 feats/slice) ============================
// Block = (bin, slice); slice = blockIdx.x & 7 -> round-robin XCD heuristic: each
// XCD gathers only its 3.2MB plane (L2-resident). 16 edges per wave-instruction
// (lane = edge*4 + quarter; quarter loads 4 bf16 = 8B), reduce over edge bits
// via shfl_xor(4/8/16/32).
template <bool SCALE>
__global__ __launch_bounds__(256) void spmm16_sliced(
    const int* __restrict__ rowptr, const int2* __restrict__ bins2,
    const unsigned short* __restrict__ Xp, const float* __restrict__ AM,
    unsigned short* __restrict__ Yp, int n) {
  const int slice = blockIdx.x & 7;
  const int bin = blockIdx.x >> 3;
  const int t = threadIdx.x;
  const int wave = t >> 6, lane = t & 63;
  const int eidx = lane >> 2, q = lane & 3;
  const unsigned short* Xs = Xp + (size_t)slice * n * 16;
  unsigned short* Ys = Yp + (size_t)slice * n * 16;
  const int row0 = bin * BINROWS;

  for (int i = 0; i < 16; ++i) {
    int row = row0 + wave * 16 + i;
    if (row >= n) break;  // wave-uniform
    int s0 = rowptr[row], d = rowptr[row + 1] - s0;
    float a0 = 0.f, a1 = 0.f, a2 = 0.f, a3 = 0.f;
    for (int kb = 0; kb < d; kb += 64) {
      int rem = min(64, d - kb);
      int2 my = (lane < rem) ? bins2[s0 + kb + lane] : make_int2(0, 0);
      int myc = my.x & 0x1FFFF;
      float myw = __int_as_float(my.y);
      int steps = (rem + 15) >> 4;
      for (int st = 0; st < steps; ++st) {
        int idx = st * 16 + eidx;  // <= 63; pad entries have w==0
        int c = __shfl(myc, idx);
        float wv = __shfl(myw, idx);
        uint2 pv = *(const uint2*)(Xs + (size_t)c * 16 + q * 4);
        a0 += wv * bf2f(pv.x);
        a1 += wv * bf2f(pv.x >> 16);
        a2 += wv * bf2f(pv.y);
        a3 += wv * bf2f(pv.y >> 16);
      }
    }
#pragma unroll
    for (int m = 4; m < 64; m <<= 1) {
      a0 += __shfl_xor(a0, m);
      a1 += __shfl_xor(a1, m);
      a2 += __shfl_xor(a2, m);
      a3 += __shfl_xor(a3, m);
    }
    if (SCALE) {
      float am = AM[row];
      a0 *= am; a1 *= am; a2 *= am; a3 *= am;
    }
    if (lane < 4) {  // lane==q, eidx==0: feats q*4..q*4+3
      uint2 pk;
      pk.x = f2bf(a0) | (f2bf(a1) << 16);
      pk.y = f2bf(a2) | (f2bf(a3) << 16);
      *(uint2*)(Ys + (size_t)row * 16 + lane * 4) = pk;
    }
  }
}

// ============================ MFMA GEMM 128x128 (+BN+ReLU), plane IO ============================
__global__ __launch_bounds__(256) void gemm_mfma128(
    const unsigned short* __restrict__ Yp, const unsigned short* __restrict__ Wb,
    const float* __restrict__ scale, const float* __restrict__ shift,
    unsigned short* __restrict__ Outp, int M) {
  const int wave = threadIdx.x >> 6;
  const int lane = threadIdx.x & 63;
  const int quad = lane >> 4;
  const int l16 = lane & 15;
  const int arow = blockIdx.x * 64 + wave * 16 + l16;
  const bool rv = arow < M;

  f32x4 acc[8];
#pragma unroll
  for (int c = 0; c < 8; ++c) acc[c] = (f32x4){0.f, 0.f, 0.f, 0.f};

#pragma unroll
  for (int kc = 0; kc < 128; kc += 32) {
    int f = kc + quad * 8;
    bf16x8 a = rv ? *(const bf16x8*)(Yp + (size_t)(f >> 4) * M * 16 + (size_t)arow * 16 + (f & 8))
                  : (bf16x8){0, 0, 0, 0, 0, 0, 0, 0};
#pragma unroll
    for (int c = 0; c < 8; ++c) {
      bf16x8 b = *(const bf16x8*)(Wb + (size_t)(c * 16 + l16) * 128 + kc + quad * 8);
      acc[c] = __builtin_amdgcn_mfma_f32_16x16x32_bf16(a, b, acc[c], 0, 0, 0);
    }
  }

  int orow0 = blockIdx.x * 64 + wave * 16 + quad * 4;
#pragma unroll
  for (int c = 0; c < 8; ++c) {
    int col = c * 16 + l16;
    float sc = scale[col], sh = shift[col];
    unsigned short* Op = Outp + (size_t)c * M * 16;  // plane c (col>>4 == c)
#pragma unroll
    for (int r = 0; r < 4; ++r) {
      int orow = orow0 + r;
      if (orow < M) {
        float v = fmaxf(acc[c][r] * sc + sh, 0.f);
        Op[(size_t)orow * 16 + l16] = (unsigned short)f2bf(v);
      }
    }
  }
}

// ============================ GEMM layer 2: plane-in, padded-bf16 out ============================
// G2[M x 64] bf16 (cols 40..63 = 0) = Y[M x 128] @ W2[40 x 128]^T.
__global__ __launch_bounds__(256) void gemm40_kernel(
    const unsigned short* __restrict__ Yp, const float* __restrict__ W,
    unsigned short* __restrict__ G2, int M, int NoutReal) {
  __shared__ float Yt[16][128];
  __shared__ float Bt[16][64];
  const int t = threadIdx.x;
  const int tx = t & 15, ty = t >> 4;
  const int row0 = blockIdx.x * 128;

  float acc[8][4];
#pragma unroll
  for (int i = 0; i < 8; ++i)
#pragma unroll
    for (int j = 0; j < 4; ++j) acc[i][j] = 0.f;

  for (int kc = 0; kc < 128; kc += 16) {
    {
      int r = t >> 1, kh = (t & 1) * 8;
      int gr = row0 + r;
      int f = kc + kh;
      uint4 v = make_uint4(0, 0, 0, 0);
      if (gr < M) v = *(const uint4*)(Yp + (size_t)(f >> 4) * M * 16 + (size_t)gr * 16 + (f & 8));
      unsigned int p;
      p = v.x; Yt[kh + 0][r] = bf2f(p); Yt[kh + 1][r] = bf2f(p >> 16);
      p = v.y; Yt[kh + 2][r] = bf2f(p); Yt[kh + 3][r] = bf2f(p >> 16);
      p = v.z; Yt[kh + 4][r] = bf2f(p); Yt[kh + 5][r] = bf2f(p >> 16);
      p = v.w; Yt[kh + 6][r] = bf2f(p); Yt[kh + 7][r] = bf2f(p >> 16);
    }
    {
      int o = t >> 2, kq = t & 3;
      float4 v = make_float4(0.f, 0.f, 0.f, 0.f);
      if (o < NoutReal) v = *(const float4*)&W[(size_t)o * 128 + kc + kq * 4];
      Bt[kq * 4 + 0][o] = v.x; Bt[kq * 4 + 1][o] = v.y;
      Bt[kq * 4 + 2][o] = v.z; Bt[kq * 4 + 3][o] = v.w;
    }
    __syncthreads();
#pragma unroll
    for (int kk = 0; kk < 16; ++kk) {
      float a[8];
      const float4* ap = (const float4*)(&Yt[kk][ty * 8]);
      float4 a0 = ap[0], a1 = ap[1];
      a[0] = a0.x; a[1] = a0.y; a[2] = a0.z; a[3] = a0.w;
      a[4] = a1.x; a[5] = a1.y; a[6] = a1.z; a[7] = a1.w;
      float4 bv = *(const float4*)(&Bt[kk][tx * 4]);
      float b[4] = {bv.x, bv.y, bv.z, bv.w};
#pragma unroll
      for (int i = 0; i < 8; ++i)
#pragma unroll
        for (int j = 0; j < 4; ++j) acc[i][j] += a[i] * b[j];
    }
    __syncthreads();
  }

#pragma unroll
  for (int i = 0; i < 8; ++i) {
    int gr = row0 + ty * 8 + i;
    if (gr < M) {  // cols >= 40 computed against zero B -> stores zeros (padding)
      uint2 pk;
      pk.x = f2bf(acc[i][0]) | (f2bf(acc[i][1]) << 16);
      pk.y = f2bf(acc[i][2]) | (f2bf(acc[i][3]) << 16);
      *(uint2*)(G2 + (size_t)gr * NCLSP + tx * 4) = pk;
    }
  }
}

// ============================ final: spmm(40) + bias + log_softmax ============================
// 4 edges per wave-instruction: lane = edge*16 + q; q loads 4 bf16 classes (8B);
// reduce over edge bits via shfl_xor(16/32). Classes 40..63 are zero padding.
__global__ __launch_bounds__(256) void spmm_softmax64(
    const int* __restrict__ rowptr, const int2* __restrict__ bins2,
    const unsigned short* __restrict__ G2, const float* __restrict__ b2,
    float* __restrict__ out, int n) {
  const int t = threadIdx.x;
  const int wave = t >> 6, lane = t & 63;
  const int eidx = lane >> 4, q = lane & 15;
  const int row0 = blockIdx.x * BINROWS;
  const bool vq = q < (NCLS / 4);  // 10 quartets cover the 40 real classes
  float4 bv = vq ? *(const float4*)(b2 + q * 4) : make_float4(0.f, 0.f, 0.f, 0.f);

  for (int i = 0; i < 16; ++i) {
    int row = row0 + wave * 16 + i;
    if (row >= n) break;
    int s0 = rowptr[row], d = rowptr[row + 1] - s0;
    float a0 = 0.f, a1 = 0.f, a2 = 0.f, a3 = 0.f;
    for (int kb = 0; kb < d; kb += 64) {
      int rem = min(64, d - kb);
      int2 my = (lane < rem) ? bins2[s0 + kb + lane] : make_int2(0, 0);
      int myc = my.x & 0x1FFFF;
      float myw = __int_as_float(my.y);
      int steps = (rem + 3) >> 2;
      for (int st = 0; st < steps; ++st) {
        int idx = st * 4 + eidx;  // <= 63; pad entries have w==0
        int c = __shfl(myc, idx);
        float wv = __shfl(myw, idx);
        uint2 pv = *(const uint2*)(G2 + (size_t)c * NCLSP + q * 4);
        a0 += wv * bf2f(pv.x);
        a1 += wv * bf2f(pv.x >> 16);
        a2 += wv * bf2f(pv.y);
        a3 += wv * bf2f(pv.y >> 16);
      }
    }
    a0 += __shfl_xor(a0, 16); a1 += __shfl_xor(a1, 16);
    a2 += __shfl_xor(a2, 16); a3 += __shfl_xor(a3, 16);
    a0 += __shfl_xor(a0, 32); a1 += __shfl_xor(a1, 32);
    a2 += __shfl_xor(a2, 32); a3 += __shfl_xor(a3, 32);
    float z0 = a0 + bv.x, z1 = a1 + bv.y, z2 = a2 + bv.z, z3 = a3 + bv.w;
    bool par = (eidx == 0) && vq;
    float m = par ? fmaxf(fmaxf(z0, z1), fmaxf(z2, z3)) : -INFINITY;
#pragma unroll
    for (int o = 1; o < 64; o <<= 1) m = fmaxf(m, __shfl_xor(m, o));
    float ex = par ? (__expf(z0 - m) + __expf(z1 - m) + __expf(z2 - m) + __expf(z3 - m)) : 0.f;
#pragma unroll
    for (int o = 1; o < 64; o <<= 1) ex += __shfl_xor(ex, o);
    float lg = m + __logf(ex);
    if (par) {
      *(float4*)&out[(size_t)row * NCLS + q * 4] =
          make_float4(z0 - lg, z1 - lg, z2 - lg, z3 - lg);
    }
  }
}

// ============================ launch ============================

extern "C" void kernel_launch(void* const* d_in, const int* in_sizes, int n_in,
                              void* d_out, int out_size, void* d_ws, size_t ws_size,
                              hipStream_t stream) {
  const float* x    = (const float*)d_in[0];
  const float* Mv   = (const float*)d_in[1];
  const float* AM   = (const float*)d_in[2];
  const int* srcZ   = (const int*)d_in[3];
  const int* dstZ   = (const int*)d_in[4];
  const float* valsZ= (const float*)d_in[5];
  const int* src    = (const int*)d_in[6];
  const int* dst    = (const int*)d_in[7];
  const float* vals = (const float*)d_in[8];
  const float* W0   = (const float*)d_in[9];
  const float* b0   = (const float*)d_in[10];
  const float* g0   = (const float*)d_in[11];
  const float* be0  = (const float*)d_in[12];
  const float* rm0  = (const float*)d_in[13];
  const float* rv0  = (const float*)d_in[14];
  const float* W1   = (const float*)d_in[15];
  const float* b1   = (const float*)d_in[16];
  const float* g1   = (const float*)d_in[17];
  const float* be1  = (const float*)d_in[18];
  const float* rm1  = (const float*)d_in[19];
  const float* rv1  = (const float*)d_in[20];
  const float* W2   = (const float*)d_in[21];
  const float* b2   = (const float*)d_in[22];
  float* out = (float*)d_out;

  const int N = in_sizes[1];  // M has shape (N,1)
  const int E = in_sizes[3];
  const int NBIN = (N + BINROWS - 1) / BINROWS;
  const int CHUNK = (E + NBLKC - 1) / NBLKC;  // 6250 <= CHUNKMAX

  char* w = (char*)d_ws;
  size_t off = 0;
  auto alloc = [&](size_t bytes) -> void* {
    void* p = w + off;
    off = (off + bytes + 255) & ~(size_t)255;
    return p;
  };
  // Z and A binning run SEQUENTIALLY through the same staging buffers (~109MB total):
  int2* binsC = (int2*)alloc((size_t)NBLKC * CHUNK * 8);   // 12.8MB chunk-ordered stage
  int2* Drm = (int2*)alloc((size_t)NBLKC * NBIN * 8);      // 3.2MB
  int2* Dbm = (int2*)alloc((size_t)NBIN * NBLKC * 8);      // 3.2MB
  int* binTot = (int*)alloc((size_t)NBIN * 4);
  int* binStart = (int*)alloc((size_t)(NBIN + 1) * 4);
  int2* bins2A = (int2*)alloc((size_t)E * 8);              // 12.8MB, lives to the end
  int* rowptrA = (int*)alloc((size_t)(N + 1) * 4);
  unsigned short* xm = (unsigned short*)alloc((size_t)N * NFEAT * 2);    // 25.6MB planes
  unsigned short* bufA = (unsigned short*)alloc((size_t)N * NFEAT * 2);  // Y planes / G2
  unsigned short* bufB = (unsigned short*)alloc((size_t)N * NFEAT * 2);  // bins2Z+rowptrZ -> H planes
  float* sc0 = (float*)alloc(128 * 4);
  float* sh0 = (float*)alloc(128 * 4);
  float* sc1 = (float*)alloc(128 * 4);
  float* sh1 = (float*)alloc(128 * 4);
  unsigned short* Wb0 = (unsigned short*)alloc(128 * 128 * 2);
  unsigned short* Wb1 = (unsigned short*)alloc(128 * 128 * 2);
  // aliases: bins2Z+rowptrZ live in bufB until spmmZ consumes them (gemm0 then
  // overwrites bufB with H0); G2 (N x 64 bf16 = 12.8MB) lives in bufA after Y1 dies.
  int2* bins2Z = (int2*)bufB;
  int* rowptrZ = (int*)((char*)bufB + 13 * 1024 * 1024);
  unsigned short* G2 = bufA;

  const int GB64 = (N + 63) / 64;
  const int GB128 = (N + 127) / 128;
  const int TDB = (NBIN + 7) / 8;

  bn_prep<<<1, 256, 0, stream>>>(b0, g0, be0, rm0, rv0, b1, g1, be1, rm1, rv1,
                                 sc0, sh0, sc1, sh1);
  convert_xm<<<(N * (NFEAT / 8) + 255) / 256, 256, 0, stream>>>(x, Mv, xm, N);
  convert_w<<<16, 256, 0, stream>>>(W0, W1, Wb0, Wb1);

  // --- adjacency Z: chunk-bin sort -> full row sort ---
  bin_sort1<<<NBLKC, 256, 0, stream>>>(srcZ, dstZ, valsZ, Drm, binsC, E, NBIN, CHUNK);
  transposeD1<<<TDB, 256, 0, stream>>>(Drm, Dbm, binTot, NBIN);
  bin_start1<<<1, 256, 0, stream>>>(binTot, binStart, NBIN);
  row_sort<<<NBIN, 256, 0, stream>>>(Dbm, binsC, binStart, bins2Z, rowptrZ, N, NBIN);

  // --- adjacency A (reuses staging) ---
  bin_sort1<<<NBLKC, 256, 0, stream>>>(src, dst, vals, Drm, binsC, E, NBIN, CHUNK);
  transposeD1<<<TDB, 256, 0, stream>>>(Drm, Dbm, binTot, NBIN);
  bin_start1<<<1, 256, 0, stream>>>(binTot, binStart, NBIN);
  row_sort<<<NBIN, 256, 0, stream>>>(Dbm, binsC, binStart, bins2A, rowptrA, N, NBIN);

  // layer 0: Y0 = spmm(adjZ, M*x)*AM ; H0 = relu(bn(Y0 @ W0^T + b0))
  spmm16_sliced<true><<<NBIN * 8, 256, 0, stream>>>(rowptrZ, bins2Z, xm, AM, bufA, N);
  gemm_mfma128<<<GB64, 256, 0, stream>>>(bufA, Wb0, sc0, sh0, bufB, N);

  // layer 1: Y1 = spmm(adj, H0) ; H1 = relu(bn(Y1 @ W1^T + b1))
  spmm16_sliced<false><<<NBIN * 8, 256, 0, stream>>>(rowptrA, bins2A, bufB,
                                                     (const float*)nullptr, bufA, N);
  gemm_mfma128<<<GB64, 256, 0, stream>>>(bufA, Wb1, sc1, sh1, bufB, N);

  // layer 2: G2 = bf16(H1 @ W2^T) padded to 64 cols (GEMM first, segment_sum linear);
  // out = log_softmax(spmm(adj, G2) + b2)
  gemm40_kernel<<<GB128, 256, 0, stream>>>(bufB, W2, G2, N, NCLS);
  spmm_softmax64<<<NBIN, 256, 0, stream>>>(rowptrA, bins2A, G2, b2, out, N);
}

// Round 9
// 574.346 us; speedup vs baseline: 1.4698x; 1.4698x over previous
//
#include <hip/hip_runtime.h>
#include <math.h>

#define NFEAT 128
#define NCLS 40
#define NCLSP 64      // padded class dim (bf16) for pow2 lane math
#define BINROWS 64    // rows per bin
#define NBINMAX 1600  // >= ceil(100000/64)=1563
#define NBLKC 256     // chunks for the binning sort
#define CHUNKMAX 6400 // >= ceil(1600000/256)=6250 ; LDS stage = 50KB
#define SEGC 7        // ceil(NBINMAX/256)
#define RSMAX 2048    // row_sort LDS stage (bin edges ~Poisson(1024))

typedef short bf16x8 __attribute__((ext_vector_type(8)));
typedef float f32x4 __attribute__((ext_vector_type(4)));

// ---------- bf16 helpers ----------
__device__ __forceinline__ float bf2f(unsigned int lo16) {
  return __uint_as_float((lo16 & 0xffffu) << 16);
}
__device__ __forceinline__ unsigned int f2bf(float x) {  // round-to-nearest-even
  unsigned int u = __float_as_uint(x);
  return (u + 0x7fffu + ((u >> 16) & 1u)) >> 16;
}

// ============================ BN param folding ============================
__global__ void bn_prep(const float* b0, const float* g0, const float* be0,
                        const float* rm0, const float* rv0,
                        const float* b1, const float* g1, const float* be1,
                        const float* rm1, const float* rv1,
                        float* sc0, float* sh0, float* sc1, float* sh1) {
  int t = threadIdx.x;
  if (t < 128) {
    float s = g0[t] * rsqrtf(rv0[t] + 1e-5f);
    sc0[t] = s;
    sh0[t] = (b0[t] - rm0[t]) * s + be0[t];
  } else {
    int i = t - 128;
    float s = g1[i] * rsqrtf(rv1[i] + 1e-5f);
    sc1[i] = s;
    sh1[i] = (b1[i] - rm1[i]) * s + be1[i];
  }
}

// ============================ input conversions (flat row-major) ============================
__global__ void convert_xm(const float* __restrict__ x, const float* __restrict__ Mv,
                           unsigned short* __restrict__ xm, int n) {
  int i = blockIdx.x * 256 + threadIdx.x;  // one 8-elem chunk per thread
  if (i >= n * (NFEAT / 8)) return;
  int row = i >> 4;
  float m = Mv[row];
  const float4* p = (const float4*)(x + (size_t)i * 8);
  float4 v0 = p[0], v1 = p[1];
  unsigned int o0 = f2bf(v0.x * m) | (f2bf(v0.y * m) << 16);
  unsigned int o1 = f2bf(v0.z * m) | (f2bf(v0.w * m) << 16);
  unsigned int o2 = f2bf(v1.x * m) | (f2bf(v1.y * m) << 16);
  unsigned int o3 = f2bf(v1.z * m) | (f2bf(v1.w * m) << 16);
  ((uint4*)xm)[i] = make_uint4(o0, o1, o2, o3);
}

__global__ void convert_w(const float* __restrict__ W0, const float* __restrict__ W1,
                          unsigned short* __restrict__ Wb0, unsigned short* __restrict__ Wb1) {
  int i = blockIdx.x * 256 + threadIdx.x;  // 4096 threads, 8 elems each
  const float* W = (i < 2048) ? W0 : W1;
  unsigned short* Wb = (i < 2048) ? Wb0 : Wb1;
  int j = (i < 2048) ? i : i - 2048;
  const float4* p = (const float4*)(W + (size_t)j * 8);
  float4 v0 = p[0], v1 = p[1];
  unsigned int o0 = f2bf(v0.x) | (f2bf(v0.y) << 16);
  unsigned int o1 = f2bf(v0.z) | (f2bf(v0.w) << 16);
  unsigned int o2 = f2bf(v1.x) | (f2bf(v1.y) << 16);
  unsigned int o3 = f2bf(v1.z) | (f2bf(v1.w) << 16);
  ((uint4*)Wb)[j] = make_uint4(o0, o1, o2, o3);
}

// ============================ stage 1: chunk -> 64-row bins (LDS sort) ============================
__global__ __launch_bounds__(256) void bin_sort1(
    const int* __restrict__ srcp, const int* __restrict__ dstp, const float* __restrict__ valp,
    int2* __restrict__ Drm, int2* __restrict__ binsC, int E, int nbin, int chunk) {
  __shared__ int2 stage[CHUNKMAX];
  __shared__ int cur[NBINMAX];
  __shared__ int ps[256];
  const int t = threadIdx.x, k = blockIdx.x;
  for (int i = t; i < nbin; i += 256) cur[i] = 0;
  __syncthreads();
  const int e0 = k * chunk, e1 = min(E, e0 + chunk);
#pragma unroll 4
  for (int e = e0 + t; e < e1; e += 256) atomicAdd(&cur[dstp[e] >> 6], 1);
  __syncthreads();
  int loc[SEGC], cnt[SEGC];
  int s = 0;
#pragma unroll
  for (int j = 0; j < SEGC; ++j) {
    int i = t * SEGC + j;
    int v = (i < nbin) ? cur[i] : 0;
    loc[j] = s; cnt[j] = v;
    s += v;
  }
  ps[t] = s;
  __syncthreads();
  for (int o = 1; o < 256; o <<= 1) {
    int x = (t >= o) ? ps[t - o] : 0;
    __syncthreads();
    ps[t] += x;
    __syncthreads();
  }
  int ex = ps[t] - s;
#pragma unroll
  for (int j = 0; j < SEGC; ++j) {
    int i = t * SEGC + j;
    if (i < nbin) {
      int o = ex + loc[j];
      Drm[(size_t)k * nbin + i] = make_int2(e0 + o, cnt[j]);
      cur[i] = o;
    }
  }
  __syncthreads();
#pragma unroll 2
  for (int e = e0 + t; e < e1; e += 256) {
    int d = dstp[e];
    int p = atomicAdd(&cur[d >> 6], 1);
    stage[p] = make_int2(srcp[e] | ((d & 63) << 17), __float_as_int(valp[e]));
  }
  __syncthreads();
  const int n = e1 - e0;
  for (int i = t; i < n; i += 256) binsC[e0 + i] = stage[i];
}

// Transpose run descriptors (row-major by chunk -> bin-major) + per-bin totals.
__global__ __launch_bounds__(256) void transposeD1(
    const int2* __restrict__ Drm, int2* __restrict__ Dbm, int* __restrict__ binTot, int nbin) {
  __shared__ int2 st[8][256];
  __shared__ int part[256];
  int t = threadIdx.x;
  int i0 = blockIdx.x * 8;
#pragma unroll
  for (int j = 0; j < 8; ++j) {
    int i = i0 + j;
    st[j][t] = (i < nbin) ? Drm[(size_t)t * nbin + i] : make_int2(0, 0);
  }
  __syncthreads();
  {
    int j = t >> 5, ks = (t & 31) * 8;
    int i = i0 + j;
    if (i < nbin) {
      int2* q = &Dbm[(size_t)i * NBLKC + ks];
#pragma unroll
      for (int m = 0; m < 8; ++m) q[m] = st[j][ks + m];
    }
    int p = 0;
#pragma unroll
    for (int m = 0; m < 8; ++m) p += st[j][ks + m].y;
    part[t] = p;
  }
  __syncthreads();
  if (t < 8) {
    int s = 0;
    for (int k = 0; k < 32; ++k) s += part[t * 32 + k];
    if (i0 + t < nbin) binTot[i0 + t] = s;
  }
}

// Exclusive scan of binTot -> binStart (single block).
__global__ __launch_bounds__(256) void bin_start1(
    const int* __restrict__ bt, int* __restrict__ bs, int nbin) {
  __shared__ int ps[256];
  int t = threadIdx.x;
  int C = (nbin + 255) / 256;  // <= 7
  int loc[SEGC + 1];
  int sum = 0;
  for (int j = 0; j < C; ++j) {
    int i = t * C + j;
    loc[j] = sum;
    sum += (i < nbin) ? bt[i] : 0;
  }
  ps[t] = sum;
  __syncthreads();
  for (int o = 1; o < 256; o <<= 1) {
    int x = (t >= o) ? ps[t - o] : 0;
    __syncthreads();
    ps[t] += x;
    __syncthreads();
  }
  int ex = ps[t] - sum;
  for (int j = 0; j < C; ++j) {
    int i = t * C + j;
    if (i < nbin) bs[i] = ex + loc[j];
  }
  if (t == 255) bs[nbin] = ps[255];
}

// ============================ stage 2: bin -> full dst-row sort ============================
__global__ __launch_bounds__(256) void row_sort(
    const int2* __restrict__ Dbm, const int2* __restrict__ binsC,
    const int* __restrict__ binStart, int2* __restrict__ bins2,
    int* __restrict__ rowptr, int n, int nbin) {
  __shared__ int2 stage[RSMAX];
  __shared__ int ps[256];
  __shared__ int rcnt[BINROWS];
  __shared__ int roff[BINROWS];
  const int b = blockIdx.x, t = threadIdx.x;
  if (t < BINROWS) rcnt[t] = 0;
  int2 run = Dbm[(size_t)b * NBLKC + t];
  ps[t] = run.y;
  __syncthreads();
  for (int o = 1; o < 256; o <<= 1) {
    int x = (t >= o) ? ps[t - o] : 0;
    __syncthreads();
    ps[t] += x;
    __syncthreads();
  }
  int mystart = ps[t] - run.y;
  for (int j = 0; j < run.y; ++j) {
    int2 en = binsC[run.x + j];
    int idx = mystart + j;
    if (idx < RSMAX) stage[idx] = en;
    atomicAdd(&rcnt[(en.x >> 17) & 63], 1);
  }
  __syncthreads();
  const int bs = binStart[b];
  if (t < BINROWS) {  // wave 0 only: scan 64 row counts
    int c = rcnt[t];
    int s = c;
#pragma unroll
    for (int o = 1; o < 64; o <<= 1) {
      int v = __shfl_up(s, o);
      if (t >= o) s += v;
    }
    int excl = s - c;
    int row = b * BINROWS + t;
    if (row < n) rowptr[row] = bs + excl;
    roff[t] = excl;
  }
  __syncthreads();
  int total = min(ps[255], RSMAX);
  for (int i = t; i < total; i += 256) {
    int2 en = stage[i];
    int row = (en.x >> 17) & 63;
    int p = atomicAdd(&roff[row], 1);
    bins2[bs + p] = en;
  }
  if (b == nbin - 1 && t == 0) rowptr[n] = binStart[nbin];
}

// ============================ SPMM (128 feats), row-sorted, no LDS ============================
// One wave per row; lane owns 4 consecutive feats (8B). Two 32-lane halves each
// gather a DIFFERENT edge per step (one full 256B X-row per edge), 4 steps
// unrolled -> 8 gathers in flight. Halves combined via shfl_xor(32).
template <bool SCALE>
__global__ __launch_bounds__(256) void spmm128_sorted(
    const int* __restrict__ rowptr, const int2* __restrict__ bins2,
    const unsigned short* __restrict__ X, const float* __restrict__ AM,
    unsigned short* __restrict__ Y, int n) {
  int row = (blockIdx.x * 256 + threadIdx.x) >> 6;
  int lane = threadIdx.x & 63;
  if (row >= n) return;
  int s = rowptr[row], d = rowptr[row + 1] - s;
  int half = lane >> 5, l32 = lane & 31;
  float s0 = 0.f, s1 = 0.f, s2 = 0.f, s3 = 0.f;
  for (int kb = 0; kb < d; kb += 64) {
    int rem = min(64, d - kb);
    int2 my = (lane < rem) ? bins2[s + kb + lane] : make_int2(0, 0);  // w==0 pads
    int myc = my.x & 0x1FFFF;
    float myw = __int_as_float(my.y);
    for (int k = 0; k < rem; k += 8) {
#pragma unroll
      for (int st = 0; st < 4; ++st) {
        int idx = k + 2 * st + half;  // <= 63; pad entries have w==0
        int c = __shfl(myc, idx);
        float wv = __shfl(myw, idx);
        uint2 pv = *(const uint2*)(X + (size_t)c * NFEAT + l32 * 4);
        s0 += wv * bf2f(pv.x);
        s1 += wv * bf2f(pv.x >> 16);
        s2 += wv * bf2f(pv.y);
        s3 += wv * bf2f(pv.y >> 16);
      }
    }
  }
  s0 += __shfl_xor(s0, 32); s1 += __shfl_xor(s1, 32);
  s2 += __shfl_xor(s2, 32); s3 += __shfl_xor(s3, 32);
  if (SCALE) {
    float am = AM[row];
    s0 *= am; s1 *= am; s2 *= am; s3 *= am;
  }
  unsigned int pk = half ? (f2bf(s2) | (f2bf(s3) << 16)) : (f2bf(s0) | (f2bf(s1) << 16));
  ((unsigned int*)Y)[(size_t)row * (NFEAT / 2) + l32 * 2 + half] = pk;
}

// ============================ MFMA GEMM 128x128 (+BN+ReLU), flat IO ============================
__global__ __launch_bounds__(256) void gemm_mfma128(
    const unsigned short* __restrict__ Y, const unsigned short* __restrict__ Wb,
    const float* __restrict__ scale, const float* __restrict__ shift,
    unsigned short* __restrict__ Out, int M) {
  const int wave = threadIdx.x >> 6;
  const int lane = threadIdx.x & 63;
  const int quad = lane >> 4;
  const int l16 = lane & 15;
  const int arow = blockIdx.x * 64 + wave * 16 + l16;
  const bool rv = arow < M;

  f32x4 acc[8];
#pragma unroll
  for (int c = 0; c < 8; ++c) acc[c] = (f32x4){0.f, 0.f, 0.f, 0.f};

#pragma unroll
  for (int kc = 0; kc < 128; kc += 32) {
    bf16x8 a = rv ? *(const bf16x8*)(Y + (size_t)arow * 128 + kc + quad * 8)
                  : (bf16x8){0, 0, 0, 0, 0, 0, 0, 0};
#pragma unroll
    for (int c = 0; c < 8; ++c) {
      bf16x8 b = *(const bf16x8*)(Wb + (size_t)(c * 16 + l16) * 128 + kc + quad * 8);
      acc[c] = __builtin_amdgcn_mfma_f32_16x16x32_bf16(a, b, acc[c], 0, 0, 0);
    }
  }

  int orow0 = blockIdx.x * 64 + wave * 16 + quad * 4;
#pragma unroll
  for (int c = 0; c < 8; ++c) {
    int col = c * 16 + l16;
    float sc = scale[col], sh = shift[col];
#pragma unroll
    for (int r = 0; r < 4; ++r) {
      int orow = orow0 + r;
      if (orow < M) {
        float v = fmaxf(acc[c][r] * sc + sh, 0.f);
        Out[(size_t)orow * 128 + col] = (unsigned short)f2bf(v);
      }
    }
  }
}

// ============================ GEMM layer 2: bf16-in, padded-bf16 out ============================
// G2[M x 64] bf16 (cols 40..63 zero) = Y[M x 128] @ W2[40 x 128]^T.
__global__ __launch_bounds__(256) void gemm40_kernel(
    const unsigned short* __restrict__ Y, const float* __restrict__ W,
    unsigned short* __restrict__ G2, int M, int NoutReal) {
  __shared__ float Yt[16][128];
  __shared__ float Bt[16][64];
  const int t = threadIdx.x;
  const int tx = t & 15, ty = t >> 4;
  const int row0 = blockIdx.x * 128;

  float acc[8][4];
#pragma unroll
  for (int i = 0; i < 8; ++i)
#pragma unroll
    for (int j = 0; j < 4; ++j) acc[i][j] = 0.f;

  for (int kc = 0; kc < 128; kc += 16) {
    {
      int r = t >> 1, kh = (t & 1) * 8;
      int gr = row0 + r;
      uint4 v = make_uint4(0, 0, 0, 0);
      if (gr < M) v = *(const uint4*)(Y + (size_t)gr * 128 + kc + kh);
      unsigned int p;
      p = v.x; Yt[kh + 0][r] = bf2f(p); Yt[kh + 1][r] = bf2f(p >> 16);
      p = v.y; Yt[kh + 2][r] = bf2f(p); Yt[kh + 3][r] = bf2f(p >> 16);
      p = v.z; Yt[kh + 4][r] = bf2f(p); Yt[kh + 5][r] = bf2f(p >> 16);
      p = v.w; Yt[kh + 6][r] = bf2f(p); Yt[kh + 7][r] = bf2f(p >> 16);
    }
    {
      int o = t >> 2, kq = t & 3;
      float4 v = make_float4(0.f, 0.f, 0.f, 0.f);
      if (o < NoutReal) v = *(const float4*)&W[(size_t)o * 128 + kc + kq * 4];
      Bt[kq * 4 + 0][o] = v.x; Bt[kq * 4 + 1][o] = v.y;
      Bt[kq * 4 + 2][o] = v.z; Bt[kq * 4 + 3][o] = v.w;
    }
    __syncthreads();
#pragma unroll
    for (int kk = 0; kk < 16; ++kk) {
      float a[8];
      const float4* ap = (const float4*)(&Yt[kk][ty * 8]);
      float4 a0 = ap[0], a1 = ap[1];
      a[0] = a0.x; a[1] = a0.y; a[2] = a0.z; a[3] = a0.w;
      a[4] = a1.x; a[5] = a1.y; a[6] = a1.z; a[7] = a1.w;
      float4 bv = *(const float4*)(&Bt[kk][tx * 4]);
      float b[4] = {bv.x, bv.y, bv.z, bv.w};
#pragma unroll
      for (int i = 0; i < 8; ++i)
#pragma unroll
        for (int j = 0; j < 4; ++j) acc[i][j] += a[i] * b[j];
    }
    __syncthreads();
  }

#pragma unroll
  for (int i = 0; i < 8; ++i) {
    int gr = row0 + ty * 8 + i;
    if (gr < M) {  // cols >= 40 computed against zero B -> stores zeros (padding)
      uint2 pk;
      pk.x = f2bf(acc[i][0]) | (f2bf(acc[i][1]) << 16);
      pk.y = f2bf(acc[i][2]) | (f2bf(acc[i][3]) << 16);
      *(uint2*)(G2 + (size_t)gr * NCLSP + tx * 4) = pk;
    }
  }
}

// ============================ final: spmm(40) + bias + log_softmax ============================
// One wave per row. 4 edges per step: lane = edge*16 + q; q loads 4 bf16 classes
// (8B; 16 lanes x 8B = one 128B G2-row). Reduce over edge bits via shfl_xor(16/32).
__global__ __launch_bounds__(256) void spmm_softmax64(
    const int* __restrict__ rowptr, const int2* __restrict__ bins2,
    const unsigned short* __restrict__ G2, const float* __restrict__ b2,
    float* __restrict__ out, int n) {
  int row = (blockIdx.x * 256 + threadIdx.x) >> 6;
  int lane = threadIdx.x & 63;
  if (row >= n) return;
  const int eidx = lane >> 4, q = lane & 15;
  const bool vq = q < (NCLS / 4);  // 10 quartets cover the 40 real classes
  float4 bv = vq ? *(const float4*)(b2 + q * 4) : make_float4(0.f, 0.f, 0.f, 0.f);

  int s0i = rowptr[row], d = rowptr[row + 1] - s0i;
  float a0 = 0.f, a1 = 0.f, a2 = 0.f, a3 = 0.f;
  for (int kb = 0; kb < d; kb += 64) {
    int rem = min(64, d - kb);
    int2 my = (lane < rem) ? bins2[s0i + kb + lane] : make_int2(0, 0);
    int myc = my.x & 0x1FFFF;
    float myw = __int_as_float(my.y);
    int steps = (rem + 3) >> 2;
#pragma unroll 4
    for (int st = 0; st < steps; ++st) {
      int idx = st * 4 + eidx;  // <= 63; pad entries have w==0
      int c = __shfl(myc, idx);
      float wv = __shfl(myw, idx);
      uint2 pv = *(const uint2*)(G2 + (size_t)c * NCLSP + q * 4);
      a0 += wv * bf2f(pv.x);
      a1 += wv * bf2f(pv.x >> 16);
      a2 += wv * bf2f(pv.y);
      a3 += wv * bf2f(pv.y >> 16);
    }
  }
  a0 += __shfl_xor(a0, 16); a1 += __shfl_xor(a1, 16);
  a2 += __shfl_xor(a2, 16); a3 += __shfl_xor(a3, 16);
  a0 += __shfl_xor(a0, 32); a1 += __shfl_xor(a1, 32);
  a2 += __shfl_xor(a2, 32); a3 += __shfl_xor(a3, 32);
  float z0 = a0 + bv.x, z1 = a1 + bv.y, z2 = a2 + bv.z, z3 = a3 + bv.w;
  bool par = (eidx == 0) && vq;
  float m = par ? fmaxf(fmaxf(z0, z1), fmaxf(z2, z3)) : -INFINITY;
#pragma unroll
  for (int o = 1; o < 64; o <<= 1) m = fmaxf(m, __shfl_xor(m, o));
  float ex = par ? (__expf(z0 - m) + __expf(z1 - m) + __expf(z2 - m) + __expf(z3 - m)) : 0.f;
#pragma unroll
  for (int o = 1; o < 64; o <<= 1) ex += __shfl_xor(ex, o);
  float lg = m + __logf(ex);
  if (par) {
    *(float4*)&out[(size_t)row * NCLS + q * 4] =
        make_float4(z0 - lg, z1 - lg, z2 - lg, z3 - lg);
  }
}

// ============================ launch ============================

extern "C" void kernel_launch(void* const* d_in, const int* in_sizes, int n_in,
                              void* d_out, int out_size, void* d_ws, size_t ws_size,
                              hipStream_t stream) {
  const float* x    = (const float*)d_in[0];
  const float* Mv   = (const float*)d_in[1];
  const float* AM   = (const float*)d_in[2];
  const int* srcZ   = (const int*)d_in[3];
  const int* dstZ   = (const int*)d_in[4];
  const float* valsZ= (const float*)d_in[5];
  const int* src    = (const int*)d_in[6];
  const int* dst    = (const int*)d_in[7];
  const float* vals = (const float*)d_in[8];
  const float* W0   = (const float*)d_in[9];
  const float* b0   = (const float*)d_in[10];
  const float* g0   = (const float*)d_in[11];
  const float* be0  = (const float*)d_in[12];
  const float* rm0  = (const float*)d_in[13];
  const float* rv0  = (const float*)d_in[14];
  const float* W1   = (const float*)d_in[15];
  const float* b1   = (const float*)d_in[16];
  const float* g1   = (const float*)d_in[17];
  const float* be1  = (const float*)d_in[18];
  const float* rm1  = (const float*)d_in[19];
  const float* rv1  = (const float*)d_in[20];
  const float* W2   = (const float*)d_in[21];
  const float* b2   = (const float*)d_in[22];
  float* out = (float*)d_out;

  const int N = in_sizes[1];  // M has shape (N,1)
  const int E = in_sizes[3];
  const int NBIN = (N + BINROWS - 1) / BINROWS;
  const int CHUNK = (E + NBLKC - 1) / NBLKC;  // 6250 <= CHUNKMAX

  char* w = (char*)d_ws;
  size_t off = 0;
  auto alloc = [&](size_t bytes) -> void* {
    void* p = w + off;
    off = (off + bytes + 255) & ~(size_t)255;
    return p;
  };
  int2* binsC = (int2*)alloc((size_t)NBLKC * CHUNK * 8);   // 12.8MB chunk-ordered stage
  int2* Drm = (int2*)alloc((size_t)NBLKC * NBIN * 8);      // 3.2MB
  int2* Dbm = (int2*)alloc((size_t)NBIN * NBLKC * 8);      // 3.2MB
  int* binTot = (int*)alloc((size_t)NBIN * 4);
  int* binStart = (int*)alloc((size_t)(NBIN + 1) * 4);
  int2* bins2A = (int2*)alloc((size_t)E * 8);              // 12.8MB, lives to the end
  int* rowptrA = (int*)alloc((size_t)(N + 1) * 4);
  unsigned short* xm = (unsigned short*)alloc((size_t)N * NFEAT * 2);    // 25.6MB
  unsigned short* bufA = (unsigned short*)alloc((size_t)N * NFEAT * 2);  // Y0/Y1 -> G2
  unsigned short* bufB = (unsigned short*)alloc((size_t)N * NFEAT * 2);  // bins2Z -> H0/H1
  float* sc0 = (float*)alloc(128 * 4);
  float* sh0 = (float*)alloc(128 * 4);
  float* sc1 = (float*)alloc(128 * 4);
  float* sh1 = (float*)alloc(128 * 4);
  unsigned short* Wb0 = (unsigned short*)alloc(128 * 128 * 2);
  unsigned short* Wb1 = (unsigned short*)alloc(128 * 128 * 2);
  // aliases: bins2Z+rowptrZ live in bufB until spmmZ consumes them (gemm0 then
  // overwrites bufB with H0); G2 (N x 64 bf16 = 12.8MB) lives in bufA after Y1 dies.
  int2* bins2Z = (int2*)bufB;
  int* rowptrZ = (int*)((char*)bufB + 13 * 1024 * 1024);
  unsigned short* G2 = bufA;

  const int RB = (N + 3) / 4;  // 4 rows (waves) per 256-thread block
  const int GB64 = (N + 63) / 64;
  const int GB128 = (N + 127) / 128;
  const int TDB = (NBIN + 7) / 8;

  bn_prep<<<1, 256, 0, stream>>>(b0, g0, be0, rm0, rv0, b1, g1, be1, rm1, rv1,
                                 sc0, sh0, sc1, sh1);
  convert_xm<<<(N * (NFEAT / 8) + 255) / 256, 256, 0, stream>>>(x, Mv, xm, N);
  convert_w<<<16, 256, 0, stream>>>(W0, W1, Wb0, Wb1);

  // --- adjacency Z: chunk-bin sort -> full row sort ---
  bin_sort1<<<NBLKC, 256, 0, stream>>>(srcZ, dstZ, valsZ, Drm, binsC, E, NBIN, CHUNK);
  transposeD1<<<TDB, 256, 0, stream>>>(Drm, Dbm, binTot, NBIN);
  bin_start1<<<1, 256, 0, stream>>>(binTot, binStart, NBIN);
  row_sort<<<NBIN, 256, 0, stream>>>(Dbm, binsC, binStart, bins2Z, rowptrZ, N, NBIN);

  // --- adjacency A (reuses staging) ---
  bin_sort1<<<NBLKC, 256, 0, stream>>>(src, dst, vals, Drm, binsC, E, NBIN, CHUNK);
  transposeD1<<<TDB, 256, 0, stream>>>(Drm, Dbm, binTot, NBIN);
  bin_start1<<<1, 256, 0, stream>>>(binTot, binStart, NBIN);
  row_sort<<<NBIN, 256, 0, stream>>>(Dbm, binsC, binStart, bins2A, rowptrA, N, NBIN);

  // layer 0: Y0 = spmm(adjZ, M*x)*AM ; H0 = relu(bn(Y0 @ W0^T + b0))
  spmm128_sorted<true><<<RB, 256, 0, stream>>>(rowptrZ, bins2Z, xm, AM, bufA, N);
  gemm_mfma128<<<GB64, 256, 0, stream>>>(bufA, Wb0, sc0, sh0, bufB, N);

  // layer 1: Y1 = spmm(adj, H0) ; H1 = relu(bn(Y1 @ W1^T + b1))
  spmm128_sorted<false><<<RB, 256, 0, stream>>>(rowptrA, bins2A, bufB,
                                                (const float*)nullptr, bufA, N);
  gemm_mfma128<<<GB64, 256, 0, stream>>>(bufA, Wb1, sc1, sh1, bufB, N);

  // layer 2: G2 = bf16(H1 @ W2^T) padded to 64 cols (GEMM first, segment_sum linear);
  // out = log_softmax(spmm(adj, G2) + b2)
  gemm40_kernel<<<GB128, 256, 0, stream>>>(bufB, W2, G2, N, NCLS);
  spmm_softmax64<<<RB, 256, 0, stream>>>(rowptrA, bins2A, G2, b2, out, N);
}